// Round 2
// baseline (213.932 us; speedup 1.0000x reference)
//
#include <hip/hip_runtime.h>

#define B_  2
#define T_  4096
#define D_  512
#define H_  8
#define HD_ 64
#define M_  (B_*T_)   // 8192 rows

typedef _Float16 h16;
typedef _Float16 v8h __attribute__((ext_vector_type(8)));
typedef float v4f __attribute__((ext_vector_type(4)));
typedef unsigned short us;

#define AS1 __attribute__((address_space(1)))
#define AS3 __attribute__((address_space(3)))

__device__ __forceinline__ float bf2f(us u){
  union { unsigned int i; float f; } v; v.i = ((unsigned int)u) << 16; return v.f;
}
__device__ __forceinline__ us f2bf(float f){
  union { float f; unsigned int u; } v; v.f = f;
  unsigned int r = v.u + 0x7FFFu + ((v.u >> 16) & 1u);
  return (us)(r >> 16);
}
__device__ __forceinline__ v4f zero4(){ v4f z; z[0]=0.f; z[1]=0.f; z[2]=0.f; z[3]=0.f; return z; }

__device__ __forceinline__ void glds16(const h16* g, h16* l){
  __builtin_amdgcn_global_load_lds((const AS1 int*)(const void*)g,
                                   (AS3 int*)(void*)l, 16, 0, 0);
}

// ---------------- fused convert: all inputs in ONE kernel -----------------------------
__global__ __launch_bounds__(256) void conv_all(
    const void* __restrict__ x, const void* __restrict__ w0, const void* __restrict__ w1,
    const void* __restrict__ w2, const void* __restrict__ w3, const void* __restrict__ bo,
    h16* __restrict__ xb, h16* __restrict__ d0, h16* __restrict__ d1,
    h16* __restrict__ d2, h16* __restrict__ d3, float* __restrict__ bof)
{
  const int bid = blockIdx.x, tid = threadIdx.x;
  const void* src; int o0; int seg;
  h16* dst = nullptr;
  if (bid < 16384)      { src = x; o0 = bid * 256; dst = xb; seg = 0; }
  else if (bid < 20480) {
    const int wsel = (bid - 16384) >> 10;
    src = (wsel == 0) ? w0 : (wsel == 1) ? w1 : (wsel == 2) ? w2 : w3;
    dst = (wsel == 0) ? d0 : (wsel == 1) ? d1 : (wsel == 2) ? d2 : d3;
    o0 = ((bid - 16384) & 1023) * 256; seg = 0;
  } else                { src = bo; o0 = (bid - 20480) * 256; seg = 1; }

  __shared__ int sflag;
  if (tid == 0) sflag = 0;
  __syncthreads();
  const float probe = bf2f(((const us*)src)[o0 + tid]);
  if (!(fabsf(probe) < 1e4f)) atomicAdd(&sflag, 1);
  __syncthreads();
  const int isf32 = (sflag != 0);
  const int i = o0 + tid;
  const float v = isf32 ? ((const float*)src)[i] : bf2f(((const us*)src)[i]);
  if (seg) bof[i] = v;
  else     dst[i] = (h16)v;
}

// ---------------- GEMM core: Y[M,512] = A[M,512]*W[512,512]^T, f16 MFMA, fp32 acc -----
__device__ __forceinline__ void stage4(const h16* __restrict__ A, const h16* __restrict__ W,
                                       int m0, int n0, int kk, h16* sA, h16* sB, int tid){
  const int colA = (tid & 3) << 3;
  const int rowT = tid >> 2;
#pragma unroll
  for (int rd = 0; rd < 2; rd++) {
    const int row = rd * 64 + rowT;
    const int f = rd * 2048 + tid * 8;
    glds16(A + (size_t)(m0 + row) * D_ + kk + colA, sA + f);
    glds16(W + (size_t)(n0 + row) * D_ + kk + colA, sB + f);
  }
}

__device__ __forceinline__ void gemm_core(const h16* __restrict__ A,
                                          const h16* __restrict__ W,
                                          int m0, int n0, h16* sA, h16* sB,
                                          v4f acc[4][4]) {
  const int tid = threadIdx.x;
  const int lane = tid & 63, wid = tid >> 6;
  const int r = lane & 15, q = lane >> 4;
#pragma unroll
  for (int i = 0; i < 4; i++)
#pragma unroll
    for (int j = 0; j < 4; j++) acc[i][j] = zero4();

  stage4(A, W, m0, n0, 0, sA, sB, tid);
#pragma unroll 1
  for (int kt = 0; kt < 16; kt++) {
    if (kt < 15) {
      const int nb = (kt + 1) & 1;
      stage4(A, W, m0, n0, (kt + 1) * 32, sA + nb * 4096, sB + nb * 4096, tid);
      asm volatile("s_waitcnt vmcnt(4)" ::: "memory");   // current tile's 4 landed
    } else {
      asm volatile("s_waitcnt vmcnt(0)" ::: "memory");
    }
    asm volatile("s_barrier" ::: "memory");
    const h16* pA = sA + (kt & 1) * 4096 + ((wid & 1) * 64 + r) * 32 + q * 8;
    const h16* pB = sB + (kt & 1) * 4096 + ((wid >> 1) * 64 + r) * 32 + q * 8;
    v8h a[4], b[4];
#pragma unroll
    for (int i = 0; i < 4; i++) a[i] = *(const v8h*)(pA + i * 512);
#pragma unroll
    for (int j = 0; j < 4; j++) b[j] = *(const v8h*)(pB + j * 512);
#pragma unroll
    for (int i = 0; i < 4; i++)
#pragma unroll
      for (int j = 0; j < 4; j++)
        acc[i][j] = __builtin_amdgcn_mfma_f32_16x16x32_f16(a[i], b[j], acc[i][j], 0, 0, 0);
    asm volatile("s_barrier" ::: "memory");              // done reading cur buffers
  }
}

// z=0 -> Q (pre-scaled by 0.125*log2e for exp2 softmax); z=1 -> K
// z=2 -> VT[b,h,hd,t'] with t' = pi-permuted within each 64-wide t-tile (PV slot order).
__global__ __launch_bounds__(256, 3) void gemm_qkv(
    const h16* __restrict__ X,
    const h16* __restrict__ Wq, const h16* __restrict__ Wk, const h16* __restrict__ Wv,
    h16* __restrict__ Qo, h16* __restrict__ Ko, h16* __restrict__ VTo)
{
  __shared__ h16 sA[2 * 4096], sB[2 * 4096];
  const h16* W = (blockIdx.z == 0) ? Wq : (blockIdx.z == 1 ? Wk : Wv);
  const int m0 = blockIdx.x * 128, n0 = blockIdx.y * 128;
  v4f acc[4][4];
  gemm_core(X, W, m0, n0, sA, sB, acc);
  const int lane = threadIdx.x & 63, wid = threadIdx.x >> 6;
  const int r = lane & 15, q = lane >> 4;
  const int wm = m0 + (wid & 1) * 64, wn = n0 + (wid >> 1) * 64;
  if (blockIdx.z == 2) {
#pragma unroll
    for (int i = 0; i < 4; i++)
#pragma unroll
      for (int j = 0; j < 4; j++)
#pragma unroll
        for (int rr = 0; rr < 4; rr++) {
          const int row = wm + i*16 + q*4 + rr;   // b*T + t
          const int col = wn + j*16 + r;          // h*64 + hd
          const int bb = row >> 12, tt = row & (T_ - 1);
          const int hh = col >> 6,  hd = col & 63;
          const int t6 = tt & 63;
          const int tperm = (tt & ~63) | (t6 & 3) | (((t6 >> 2) & 3) << 3)
                          | (((t6 >> 4) & 1) << 2) | (t6 & 32);
          VTo[((size_t)(((bb << 3) + hh) << 6) + hd) * T_ + tperm] = (h16)acc[i][j][rr];
        }
  } else {
    h16* Y = (blockIdx.z == 0) ? Qo : Ko;
    const float sc = (blockIdx.z == 0) ? 0.1803368801f : 1.0f;  // 1/8 * log2(e)
#pragma unroll
    for (int i = 0; i < 4; i++)
#pragma unroll
      for (int j = 0; j < 4; j++)
#pragma unroll
        for (int rr = 0; rr < 4; rr++)
          Y[(size_t)(wm + i*16 + q*4 + rr) * D_ + wn + j*16 + r] = (h16)(acc[i][j][rr] * sc);
  }
}

__global__ __launch_bounds__(256, 3) void gemm_out(
    const h16* __restrict__ A, const h16* __restrict__ W,
    const float* __restrict__ bias, void* __restrict__ out, const void* __restrict__ xprobe)
{
  __shared__ h16 sA[2 * 4096], sB[2 * 4096];
  __shared__ int sflag;
  if (threadIdx.x == 0) sflag = 0;
  __syncthreads();
  const float probe = bf2f(((const us*)xprobe)[threadIdx.x]);
  if (!(fabsf(probe) < 1e4f)) atomicAdd(&sflag, 1);
  __syncthreads();
  const int flag = (sflag != 0);

  const int m0 = blockIdx.x * 128, n0 = blockIdx.y * 128;
  v4f acc[4][4];
  gemm_core(A, W, m0, n0, sA, sB, acc);
  const int lane = threadIdx.x & 63, wid = threadIdx.x >> 6;
  const int r = lane & 15, q = lane >> 4;
  const int wm = m0 + (wid & 1) * 64, wn = n0 + (wid >> 1) * 64;
#pragma unroll
  for (int i = 0; i < 4; i++)
#pragma unroll
    for (int j = 0; j < 4; j++)
#pragma unroll
      for (int rr = 0; rr < 4; rr++) {
        const int row = wm + i*16 + q*4 + rr;
        const int col = wn + j*16 + r;
        const float v = acc[i][j][rr] + bias[col];
        if (flag) ((float*)out)[(size_t)row * D_ + col] = v;
        else ((us*)out)[(size_t)row * D_ + col] = f2bf(v);
      }
}

// ---------------- cooperative flash attention (f16, q-block 128, 2 q-groups/wave) ----
// ROUND 12: each wave now owns TWO 16-row q-groups (rows qc*128 + wid*16 + g*64), so
// ka/va LDS fragments + staging + barriers amortize over 32 q-rows (halves per-entry
// VALU), and the two independent q-group chains give intra-wave ILP to hide the
// exp2->cvt->MFMA dependency at 2 blocks/CU occupancy. Interleaved group layout makes
// every wave's diagonal tile identical (diag_g = 2*qc+g, uniform across waves; mask
// predicate collapses to i*16+quad*4+rr <= wid*16+r). Group 0 is fully masked at the
// final tile and skipped by a uniform branch. Staging addresses strength-reduced to
// running pointers. 512 blocks, all resident (2/CU): slot pairing (s, s+32) gives
// qc + qc' = 31 => per-CU tile sums constant; heavy half dispatched first.
__global__ __launch_bounds__(256, 2) void attn_kernel(
    const h16* __restrict__ Q, const h16* __restrict__ K,
    const h16* __restrict__ VT, h16* __restrict__ Ctx)
{
  const int h = blockIdx.x;
  const int s = blockIdx.y + (blockIdx.z << 5);        // dispatch slot 0..63
  const int qc = (s < 32) ? (31 - (s >> 1)) : ((s - 32) >> 1);
  const int b  = s & 1;
  const int tid = threadIdx.x;
  const int wid = tid >> 6, lane = tid & 63;
  const int r = lane & 15, quad = lane >> 4;

  const size_t headoff = (size_t)b * T_ * D_ + (size_t)h * HD_;
  const h16* Qh  = Q + headoff;
  const h16* Kh  = K + headoff;
  const h16* VTh = VT + (size_t)(b * H_ + h) * HD_ * T_;
  h16* Ch = Ctx + headoff;

  __shared__ h16 sK[2][4096];
  __shared__ h16 sV[2][4096];

  const int qg0 = qc * 128 + wid * 16;                 // group 0 rows
  const int qg1 = qg0 + 64;                            // group 1 rows
  const int ntiles = 2 * qc + 2;
  const int diag0 = 2 * qc, diag1 = 2 * qc + 1;

  // Q fragments (B-operand of swapped QK^T)
  const v8h aq00 = *(const v8h*)(Qh + (size_t)(qg0 + r) * D_ + quad * 8);
  const v8h aq01 = *(const v8h*)(Qh + (size_t)(qg0 + r) * D_ + 32 + quad * 8);
  const v8h aq10 = *(const v8h*)(Qh + (size_t)(qg1 + r) * D_ + quad * 8);
  const v8h aq11 = *(const v8h*)(Qh + (size_t)(qg1 + r) * D_ + 32 + quad * 8);

  v4f o0[4], o1[4];
#pragma unroll
  for (int j = 0; j < 4; j++) { o0[j] = zero4(); o1[j] = zero4(); }
  float lsum0 = 0.f, lsum1 = 0.f;

  // staging: strength-reduced running pointers (element units)
  const int u0 = tid, u1 = tid + 256;
  const int sr0 = u0 >> 3, sj0 = (u0 & 7) ^ (sr0 & 7);
  const int sr1 = u1 >> 3, sj1 = (u1 & 7) ^ (sr1 & 7);
  const h16* kp0 = Kh + (size_t)sr0 * D_ + sj0 * 8;
  const h16* kp1 = Kh + (size_t)sr1 * D_ + sj1 * 8;
  const h16* vp0 = VTh + (size_t)sr0 * T_ + sj0 * 8;
  const h16* vp1 = VTh + (size_t)sr1 * T_ + sj1 * 8;

  // stage tile 0
  glds16(kp0, &sK[0][u0 * 8]);
  glds16(kp1, &sK[0][u1 * 8]);
  glds16(vp0, &sV[0][u0 * 8]);
  glds16(vp1, &sV[0][u1 * 8]);
  kp0 += 64 * D_; kp1 += 64 * D_; vp0 += 64; vp1 += 64;

#pragma unroll 1
  for (int kt = 0; kt < ntiles; kt++) {
    const h16* sKc = sK[kt & 1];
    const h16* sVc = sV[kt & 1];
    if (kt + 1 < ntiles) {
      const int nb = (kt + 1) & 1;
      glds16(kp0, &sK[nb][u0 * 8]);
      glds16(kp1, &sK[nb][u1 * 8]);
      glds16(vp0, &sV[nb][u0 * 8]);
      glds16(vp1, &sV[nb][u1 * 8]);
      kp0 += 64 * D_; kp1 += 64 * D_; vp0 += 64; vp1 += 64;
      asm volatile("s_waitcnt vmcnt(4)" ::: "memory");   // current tile's 4 landed
    } else {
      asm volatile("s_waitcnt vmcnt(0)" ::: "memory");
    }
    asm volatile("s_barrier" ::: "memory");

    v8h ka[8], va[8];
    // K fragments: rowk&7 == r&7 (16 | stride), so XOR term is kf-invariant
#pragma unroll
    for (int kf = 0; kf < 4; kf++) {
      const int rowk = kf * 16 + r;
      const h16* base = sKc + rowk * 64;
      ka[2*kf]   = *(const v8h*)(base + ((quad     ^ (r & 7)) * 8));
      ka[2*kf+1] = *(const v8h*)(base + (((quad+4) ^ (r & 7)) * 8));
    }
#pragma unroll
    for (int j = 0; j < 4; j++) {
      const int rowv = j * 16 + r;
      const h16* base = sVc + rowv * 64;
      va[2*j]   = *(const v8h*)(base + ((quad     ^ (r & 7)) * 8));
      va[2*j+1] = *(const v8h*)(base + (((quad+4) ^ (r & 7)) * 8));
    }

#define GROUP_COMPUTE(AQ0, AQ1, OARR, LSUM, DIAG)                              \
    {                                                                          \
      v4f s_[4];                                                               \
      _Pragma("unroll")                                                        \
      for (int i = 0; i < 4; i++) {                                            \
        v4f t = zero4();                                                       \
        t = __builtin_amdgcn_mfma_f32_16x16x32_f16(ka[2*i],   AQ0, t, 0,0,0);  \
        t = __builtin_amdgcn_mfma_f32_16x16x32_f16(ka[2*i+1], AQ1, t, 0,0,0);  \
        s_[i] = t;                                                             \
      }                                                                        \
      const bool dg_ = (kt == (DIAG));                                         \
      v8h pa0, pa1;                                                            \
      _Pragma("unroll")                                                        \
      for (int i = 0; i < 4; i++) {                                            \
        _Pragma("unroll")                                                      \
        for (int rr = 0; rr < 4; rr++) {                                       \
          float scv = s_[i][rr];                                               \
          if (dg_) scv = (i*16 + quad*4 + rr <= wid*16 + r) ? scv : -1e30f;    \
          const float e = exp2f(scv);                                          \
          LSUM += e;                                                           \
          if (i < 2) pa0[i*4+rr] = (h16)e; else pa1[(i-2)*4+rr] = (h16)e;      \
        }                                                                      \
      }                                                                        \
      _Pragma("unroll")                                                        \
      for (int j = 0; j < 4; j++) {                                            \
        OARR[j] = __builtin_amdgcn_mfma_f32_16x16x32_f16(pa0, va[2*j],   OARR[j], 0,0,0); \
        OARR[j] = __builtin_amdgcn_mfma_f32_16x16x32_f16(pa1, va[2*j+1], OARR[j], 0,0,0); \
      }                                                                        \
    }

    if (kt <= diag0) GROUP_COMPUTE(aq00, aq01, o0, lsum0, diag0);  // g0 (skips last tile)
    GROUP_COMPUTE(aq10, aq11, o1, lsum1, diag1);                   // g1 (always active)
#undef GROUP_COMPUTE

    asm volatile("s_barrier" ::: "memory");              // done reading cur buffers
  }

  // epilogue per group: reduce lane-local l over the 4 quads, normalize, store
#pragma unroll
  for (int g = 0; g < 2; g++) {
    const float lsum = g ? lsum1 : lsum0;
    const int qg = g ? qg1 : qg0;
    v4f* o = g ? o1 : o0;
    float l = lsum;
    l += __shfl_xor(l, 16, 64);
    l += __shfl_xor(l, 32, 64);
    const float inv = 1.0f / l;                // full denom for q = qg + r
    float invr[4];
#pragma unroll
    for (int rr = 0; rr < 4; rr++) invr[rr] = __shfl(inv, quad * 4 + rr, 16);
#pragma unroll
    for (int rr = 0; rr < 4; rr++) {
      const size_t row = (size_t)(qg + quad * 4 + rr) * D_;
#pragma unroll
      for (int j = 0; j < 4; j++)
        Ch[row + j * 16 + r] = (h16)(o[j][rr] * invr[rr]);
    }
  }
}

// ---------------- launch ----------------
extern "C" void kernel_launch(void* const* d_in, const int* in_sizes, int n_in,
                              void* d_out, int out_size, void* d_ws, size_t ws_size,
                              hipStream_t stream) {
  char* ws = (char*)d_ws;
  h16* xb  = (h16*)(ws + 0);                   // 8 MiB X f16
  h16* qb  = (h16*)(ws + 8388608);             // 8 MiB Q (pre-scaled by 0.125*log2e)
  h16* kb  = (h16*)(ws + 16777216);            // 8 MiB K
  h16* vt  = (h16*)(ws + 25165824);            // 8 MiB V^T (pi-permuted cols)
  h16* ctx = (h16*)(ws + 33554432);            // 8 MiB attention output
  h16* wqb = (h16*)(ws + 41943040);            // 512 KiB each
  h16* wkb = (h16*)(ws + 41943040 + 524288);
  h16* wvb = (h16*)(ws + 41943040 + 2 * 524288);
  h16* wob = (h16*)(ws + 41943040 + 3 * 524288);
  float* bof = (float*)(ws + 41943040 + 4 * 524288);

  conv_all<<<20482, 256, 0, stream>>>(d_in[0], d_in[1], d_in[2], d_in[3], d_in[4],
                                      d_in[5], xb, wqb, wkb, wvb, wob, bof);
  gemm_qkv<<<dim3(M_ / 128, D_ / 128, 3), 256, 0, stream>>>(xb, wqb, wkb, wvb, qb, kb, vt);
  attn_kernel<<<dim3(H_, 32, B_), 256, 0, stream>>>(qb, kb, vt, ctx);
  gemm_out<<<dim3(M_ / 128, D_ / 128, 1), 256, 0, stream>>>(ctx, wob, bof, d_out, d_in[0]);
}

// Round 3
// 188.036 us; speedup vs baseline: 1.1377x; 1.1377x over previous
//
#include <hip/hip_runtime.h>

#define B_  2
#define T_  4096
#define D_  512
#define H_  8
#define HD_ 64
#define M_  (B_*T_)   // 8192 rows

typedef _Float16 h16;
typedef _Float16 v8h __attribute__((ext_vector_type(8)));
typedef _Float16 h2  __attribute__((ext_vector_type(2)));
typedef float v4f __attribute__((ext_vector_type(4)));
typedef unsigned short us;

#define AS1 __attribute__((address_space(1)))
#define AS3 __attribute__((address_space(3)))

__device__ __forceinline__ float bf2f(us u){
  union { unsigned int i; float f; } v; v.i = ((unsigned int)u) << 16; return v.f;
}
__device__ __forceinline__ us f2bf(float f){
  union { float f; unsigned int u; } v; v.f = f;
  unsigned int r = v.u + 0x7FFFu + ((v.u >> 16) & 1u);
  return (us)(r >> 16);
}
__device__ __forceinline__ v4f zero4(){ v4f z; z[0]=0.f; z[1]=0.f; z[2]=0.f; z[3]=0.f; return z; }

__device__ __forceinline__ void glds16(const h16* g, h16* l){
  __builtin_amdgcn_global_load_lds((const AS1 int*)(const void*)g,
                                   (AS3 int*)(void*)l, 16, 0, 0);
}

__device__ __forceinline__ h2 pkrtz(float a, float b){
  auto t = __builtin_amdgcn_cvt_pkrtz(a, b);   // v_cvt_pkrtz_f16_f32: {f16(a),f16(b)}
  h2 r; __builtin_memcpy(&r, &t, sizeof(r)); return r;
}

// ---------------- fused convert: all inputs in ONE kernel -----------------------------
__global__ __launch_bounds__(256) void conv_all(
    const void* __restrict__ x, const void* __restrict__ w0, const void* __restrict__ w1,
    const void* __restrict__ w2, const void* __restrict__ w3, const void* __restrict__ bo,
    h16* __restrict__ xb, h16* __restrict__ d0, h16* __restrict__ d1,
    h16* __restrict__ d2, h16* __restrict__ d3, float* __restrict__ bof)
{
  const int bid = blockIdx.x, tid = threadIdx.x;
  const void* src; int o0; int seg;
  h16* dst = nullptr;
  if (bid < 16384)      { src = x; o0 = bid * 256; dst = xb; seg = 0; }
  else if (bid < 20480) {
    const int wsel = (bid - 16384) >> 10;
    src = (wsel == 0) ? w0 : (wsel == 1) ? w1 : (wsel == 2) ? w2 : w3;
    dst = (wsel == 0) ? d0 : (wsel == 1) ? d1 : (wsel == 2) ? d2 : d3;
    o0 = ((bid - 16384) & 1023) * 256; seg = 0;
  } else                { src = bo; o0 = (bid - 20480) * 256; seg = 1; }

  __shared__ int sflag;
  if (tid == 0) sflag = 0;
  __syncthreads();
  const float probe = bf2f(((const us*)src)[o0 + tid]);
  if (!(fabsf(probe) < 1e4f)) atomicAdd(&sflag, 1);
  __syncthreads();
  const int isf32 = (sflag != 0);
  const int i = o0 + tid;
  const float v = isf32 ? ((const float*)src)[i] : bf2f(((const us*)src)[i]);
  if (seg) bof[i] = v;
  else     dst[i] = (h16)v;
}

// ---------------- GEMM core: Y[M,512] = A[M,512]*W[512,512]^T, f16 MFMA, fp32 acc -----
__device__ __forceinline__ void stage4(const h16* __restrict__ A, const h16* __restrict__ W,
                                       int m0, int n0, int kk, h16* sA, h16* sB, int tid){
  const int colA = (tid & 3) << 3;
  const int rowT = tid >> 2;
#pragma unroll
  for (int rd = 0; rd < 2; rd++) {
    const int row = rd * 64 + rowT;
    const int f = rd * 2048 + tid * 8;
    glds16(A + (size_t)(m0 + row) * D_ + kk + colA, sA + f);
    glds16(W + (size_t)(n0 + row) * D_ + kk + colA, sB + f);
  }
}

__device__ __forceinline__ void gemm_core(const h16* __restrict__ A,
                                          const h16* __restrict__ W,
                                          int m0, int n0, h16* sA, h16* sB,
                                          v4f acc[4][4]) {
  const int tid = threadIdx.x;
  const int lane = tid & 63, wid = tid >> 6;
  const int r = lane & 15, q = lane >> 4;
#pragma unroll
  for (int i = 0; i < 4; i++)
#pragma unroll
    for (int j = 0; j < 4; j++) acc[i][j] = zero4();

  stage4(A, W, m0, n0, 0, sA, sB, tid);
#pragma unroll 1
  for (int kt = 0; kt < 16; kt++) {
    if (kt < 15) {
      const int nb = (kt + 1) & 1;
      stage4(A, W, m0, n0, (kt + 1) * 32, sA + nb * 4096, sB + nb * 4096, tid);
      asm volatile("s_waitcnt vmcnt(4)" ::: "memory");   // current tile's 4 landed
    } else {
      asm volatile("s_waitcnt vmcnt(0)" ::: "memory");
    }
    asm volatile("s_barrier" ::: "memory");
    const h16* pA = sA + (kt & 1) * 4096 + ((wid & 1) * 64 + r) * 32 + q * 8;
    const h16* pB = sB + (kt & 1) * 4096 + ((wid >> 1) * 64 + r) * 32 + q * 8;
    v8h a[4], b[4];
#pragma unroll
    for (int i = 0; i < 4; i++) a[i] = *(const v8h*)(pA + i * 512);
#pragma unroll
    for (int j = 0; j < 4; j++) b[j] = *(const v8h*)(pB + j * 512);
#pragma unroll
    for (int i = 0; i < 4; i++)
#pragma unroll
      for (int j = 0; j < 4; j++)
        acc[i][j] = __builtin_amdgcn_mfma_f32_16x16x32_f16(a[i], b[j], acc[i][j], 0, 0, 0);
    asm volatile("s_barrier" ::: "memory");              // done reading cur buffers
  }
}

// z=0 -> Q (pre-scaled by 0.125*log2e for exp2 softmax); z=1 -> K
// z=2 -> VT[b,h,hd,t'] with t' = pi-permuted within each 64-wide t-tile (PV slot order).
__global__ __launch_bounds__(256, 3) void gemm_qkv(
    const h16* __restrict__ X,
    const h16* __restrict__ Wq, const h16* __restrict__ Wk, const h16* __restrict__ Wv,
    h16* __restrict__ Qo, h16* __restrict__ Ko, h16* __restrict__ VTo)
{
  __shared__ h16 sA[2 * 4096], sB[2 * 4096];
  const h16* W = (blockIdx.z == 0) ? Wq : (blockIdx.z == 1 ? Wk : Wv);
  const int m0 = blockIdx.x * 128, n0 = blockIdx.y * 128;
  v4f acc[4][4];
  gemm_core(X, W, m0, n0, sA, sB, acc);
  const int lane = threadIdx.x & 63, wid = threadIdx.x >> 6;
  const int r = lane & 15, q = lane >> 4;
  const int wm = m0 + (wid & 1) * 64, wn = n0 + (wid >> 1) * 64;
  if (blockIdx.z == 2) {
#pragma unroll
    for (int i = 0; i < 4; i++)
#pragma unroll
      for (int j = 0; j < 4; j++)
#pragma unroll
        for (int rr = 0; rr < 4; rr++) {
          const int row = wm + i*16 + q*4 + rr;   // b*T + t
          const int col = wn + j*16 + r;          // h*64 + hd
          const int bb = row >> 12, tt = row & (T_ - 1);
          const int hh = col >> 6,  hd = col & 63;
          const int t6 = tt & 63;
          const int tperm = (tt & ~63) | (t6 & 3) | (((t6 >> 2) & 3) << 3)
                          | (((t6 >> 4) & 1) << 2) | (t6 & 32);
          VTo[((size_t)(((bb << 3) + hh) << 6) + hd) * T_ + tperm] = (h16)acc[i][j][rr];
        }
  } else {
    h16* Y = (blockIdx.z == 0) ? Qo : Ko;
    const float sc = (blockIdx.z == 0) ? 0.1803368801f : 1.0f;  // 1/8 * log2(e)
#pragma unroll
    for (int i = 0; i < 4; i++)
#pragma unroll
      for (int j = 0; j < 4; j++)
#pragma unroll
        for (int rr = 0; rr < 4; rr++)
          Y[(size_t)(wm + i*16 + q*4 + rr) * D_ + wn + j*16 + r] = (h16)(acc[i][j][rr] * sc);
  }
}

__global__ __launch_bounds__(256, 3) void gemm_out(
    const h16* __restrict__ A, const h16* __restrict__ W,
    const float* __restrict__ bias, void* __restrict__ out, const void* __restrict__ xprobe)
{
  __shared__ h16 sA[2 * 4096], sB[2 * 4096];
  __shared__ int sflag;
  if (threadIdx.x == 0) sflag = 0;
  __syncthreads();
  const float probe = bf2f(((const us*)xprobe)[threadIdx.x]);
  if (!(fabsf(probe) < 1e4f)) atomicAdd(&sflag, 1);
  __syncthreads();
  const int flag = (sflag != 0);

  const int m0 = blockIdx.x * 128, n0 = blockIdx.y * 128;
  v4f acc[4][4];
  gemm_core(A, W, m0, n0, sA, sB, acc);
  const int lane = threadIdx.x & 63, wid = threadIdx.x >> 6;
  const int r = lane & 15, q = lane >> 4;
  const int wm = m0 + (wid & 1) * 64, wn = n0 + (wid >> 1) * 64;
#pragma unroll
  for (int i = 0; i < 4; i++)
#pragma unroll
    for (int j = 0; j < 4; j++)
#pragma unroll
      for (int rr = 0; rr < 4; rr++) {
        const int row = wm + i*16 + q*4 + rr;
        const int col = wn + j*16 + r;
        const float v = acc[i][j][rr] + bias[col];
        if (flag) ((float*)out)[(size_t)row * D_ + col] = v;
        else ((us*)out)[(size_t)row * D_ + col] = f2bf(v);
      }
}

// ---------------- cooperative flash attention (f16, q-tile 64, strict LPT) -----------
// ROUND 13: round-1 structure (1024 blocks, q-tile 64 — restores occupancy after the
// round-12 regression) + VALU-issue reduction:
//   * v_cvt_pkrtz_f16_f32 packs P pairs directly into the PV A-frag (kills 16 scalar
//     cvts + ~24 register-insert packing ops per tile per wave)
//   * row-sum of P via ones-MFMA into a spare v4f accumulator (kills 16 f32 adds/tile
//     AND the epilogue cross-lane shuffles: denominator for output row quad*4+rr is
//     lane-local ol[rr]; normalization now uses exactly the f16-rounded P that weights V)
//   * hoisted XOR lane-bases (rowk&7 == r&7) + immediate-offset ds_reads; staging
//     addresses strength-reduced to running pointers.
__global__ __launch_bounds__(256, 4) void attn_kernel(
    const h16* __restrict__ Q, const h16* __restrict__ K,
    const h16* __restrict__ VT, h16* __restrict__ Ctx)
{
  const int h = blockIdx.x;
  const int pos = blockIdx.y + (blockIdx.z << 6);      // dispatch position 0..127
  const int qc = 63 - (pos >> 1);                      // strict LPT: heavy first
  const int b  = pos & 1;
  const int tid = threadIdx.x;
  const int wid = tid >> 6, lane = tid & 63;
  const int r = lane & 15, quad = lane >> 4;

  const size_t headoff = (size_t)b * T_ * D_ + (size_t)h * HD_;
  const h16* Qh  = Q + headoff;
  const h16* Kh  = K + headoff;
  const h16* VTh = VT + (size_t)(b * H_ + h) * HD_ * T_;
  h16* Ch = Ctx + headoff;

  __shared__ h16 sK[2][4096];
  __shared__ h16 sV[2][4096];

  const int qrow = qc * 64 + wid * 16;
  const int ntiles = qc + 1;

  // Q fragment (B-operand of swapped QK^T)
  const v8h aq0 = *(const v8h*)(Qh + (size_t)(qrow + r) * D_ + quad * 8);
  const v8h aq1 = *(const v8h*)(Qh + (size_t)(qrow + r) * D_ + 32 + quad * 8);

  v8h vone;
#pragma unroll
  for (int e = 0; e < 8; e++) vone[e] = (h16)1;

  v4f o[4];
#pragma unroll
  for (int j = 0; j < 4; j++) o[j] = zero4();
  v4f ol = zero4();                                    // row-sum accumulator (denominator)

  // staging: strength-reduced running pointers; thread covers rows {tid>>3, 32+(tid>>3)}
  const int srow = tid >> 3;                           // 0..31
  const int sj = (tid & 7) ^ (srow & 7);               // XOR-swizzled 8-elem chunk
  const h16* kcur = Kh + (size_t)srow * D_ + sj * 8;
  const h16* vcur = VTh + (size_t)srow * T_ + sj * 8;
  h16* const dK0 = &sK[0][tid * 8], * const dK0b = &sK[0][2048 + tid * 8];
  h16* const dV0 = &sV[0][tid * 8], * const dV0b = &sV[0][2048 + tid * 8];
  h16* const dK1 = &sK[1][tid * 8], * const dK1b = &sK[1][2048 + tid * 8];
  h16* const dV1 = &sV[1][tid * 8], * const dV1b = &sV[1][2048 + tid * 8];

  // stage tile 0
  glds16(kcur, dK0); glds16(kcur + 32 * D_, dK0b);
  glds16(vcur, dV0); glds16(vcur + 32 * T_, dV0b);
  kcur += 64 * D_; vcur += 64;

  // hoisted LDS lane-base offsets (element units)
  const int xo0 = (quad ^ (r & 7)) * 8;
  const int xo1 = ((quad + 4) ^ (r & 7)) * 8;

#pragma unroll 1
  for (int kt = 0; kt < ntiles; kt++) {
    const h16* sKc = sK[kt & 1];
    const h16* sVc = sV[kt & 1];
    if (kt + 1 < ntiles) {
      if ((kt + 1) & 1) {
        glds16(kcur, dK1); glds16(kcur + 32 * D_, dK1b);
        glds16(vcur, dV1); glds16(vcur + 32 * T_, dV1b);
      } else {
        glds16(kcur, dK0); glds16(kcur + 32 * D_, dK0b);
        glds16(vcur, dV0); glds16(vcur + 32 * T_, dV0b);
      }
      kcur += 64 * D_; vcur += 64;
      asm volatile("s_waitcnt vmcnt(4)" ::: "memory");   // current tile's 4 landed
    } else {
      asm volatile("s_waitcnt vmcnt(0)" ::: "memory");
    }
    asm volatile("s_barrier" ::: "memory");

    const h16* bK0 = sKc + r * 64 + xo0;
    const h16* bK1 = sKc + r * 64 + xo1;
    const h16* bV0 = sVc + r * 64 + xo0;
    const h16* bV1 = sVc + r * 64 + xo1;
    v8h ka[8], va[8];
#pragma unroll
    for (int kf = 0; kf < 4; kf++) {
      ka[2*kf]   = *(const v8h*)(bK0 + kf * 1024);
      ka[2*kf+1] = *(const v8h*)(bK1 + kf * 1024);
    }
#pragma unroll
    for (int j = 0; j < 4; j++) {
      va[2*j]   = *(const v8h*)(bV0 + j * 1024);
      va[2*j+1] = *(const v8h*)(bV1 + j * 1024);
    }
    // swapped QK^T: S^T row = k (kb+16i+quad*4+rr), col = q (qrow + r)
    v4f s_[4];
#pragma unroll
    for (int i = 0; i < 4; i++) {
      v4f t = zero4();
      t = __builtin_amdgcn_mfma_f32_16x16x32_f16(ka[2*i],   aq0, t, 0, 0, 0);
      t = __builtin_amdgcn_mfma_f32_16x16x32_f16(ka[2*i+1], aq1, t, 0, 0, 0);
      s_[i] = t;
    }
    // in-register softmax: packed f16 conversion straight into PV A-frags
    const bool dg = (kt == ntiles - 1);   // diagonal tile (exact for q-tile 64)
    union { v8h v; h2 p[4]; } pA, pB;
#pragma unroll
    for (int i = 0; i < 4; i++) {
      float e[4];
#pragma unroll
      for (int rr = 0; rr < 4; rr++) {
        float scv = s_[i][rr];            // scale pre-folded into Q
        if (dg) scv = (i * 16 + quad * 4 + rr <= wid * 16 + r) ? scv : -1e30f;
        e[rr] = exp2f(scv);               // bare v_exp_f32
      }
      const h2 p01 = pkrtz(e[0], e[1]);
      const h2 p23 = pkrtz(e[2], e[3]);
      if (i < 2) { pA.p[i * 2] = p01; pA.p[i * 2 + 1] = p23; }
      else       { pB.p[(i - 2) * 2] = p01; pB.p[(i - 2) * 2 + 1] = p23; }
    }
    // denominator via ones-MFMA (row-sum of P), then PV
    ol = __builtin_amdgcn_mfma_f32_16x16x32_f16(pA.v, vone, ol, 0, 0, 0);
    ol = __builtin_amdgcn_mfma_f32_16x16x32_f16(pB.v, vone, ol, 0, 0, 0);
#pragma unroll
    for (int j = 0; j < 4; j++) {
      o[j] = __builtin_amdgcn_mfma_f32_16x16x32_f16(pA.v, va[2*j],   o[j], 0, 0, 0);
      o[j] = __builtin_amdgcn_mfma_f32_16x16x32_f16(pB.v, va[2*j+1], o[j], 0, 0, 0);
    }
    asm volatile("s_barrier" ::: "memory");              // done reading cur buffers
  }
  // epilogue: denominator for output row (quad*4+rr) is lane-local ol[rr]
#pragma unroll
  for (int rr = 0; rr < 4; rr++) {
    const float inv = 1.0f / ol[rr];
    const size_t row = (size_t)(qrow + quad * 4 + rr) * D_;
#pragma unroll
    for (int j = 0; j < 4; j++)
      Ch[row + j * 16 + r] = (h16)(o[j][rr] * inv);
  }
}

// ---------------- launch ----------------
extern "C" void kernel_launch(void* const* d_in, const int* in_sizes, int n_in,
                              void* d_out, int out_size, void* d_ws, size_t ws_size,
                              hipStream_t stream) {
  char* ws = (char*)d_ws;
  h16* xb  = (h16*)(ws + 0);                   // 8 MiB X f16
  h16* qb  = (h16*)(ws + 8388608);             // 8 MiB Q (pre-scaled by 0.125*log2e)
  h16* kb  = (h16*)(ws + 16777216);            // 8 MiB K
  h16* vt  = (h16*)(ws + 25165824);            // 8 MiB V^T (pi-permuted cols)
  h16* ctx = (h16*)(ws + 33554432);            // 8 MiB attention output
  h16* wqb = (h16*)(ws + 41943040);            // 512 KiB each
  h16* wkb = (h16*)(ws + 41943040 + 524288);
  h16* wvb = (h16*)(ws + 41943040 + 2 * 524288);
  h16* wob = (h16*)(ws + 41943040 + 3 * 524288);
  float* bof = (float*)(ws + 41943040 + 4 * 524288);

  conv_all<<<20482, 256, 0, stream>>>(d_in[0], d_in[1], d_in[2], d_in[3], d_in[4],
                                      d_in[5], xb, wqb, wkb, wvb, wob, bof);
  gemm_qkv<<<dim3(M_ / 128, D_ / 128, 3), 256, 0, stream>>>(xb, wqb, wkb, wvb, qb, kb, vt);
  attn_kernel<<<dim3(H_, 64, B_), 256, 0, stream>>>(qb, kb, vt, ctx);
  gemm_out<<<dim3(M_ / 128, D_ / 128, 1), 256, 0, stream>>>(ctx, wob, bof, d_out, d_in[0]);
}